// Round 3
// baseline (11908.733 us; speedup 1.0000x reference)
//
#include <hip/hip_runtime.h>

#define N_PTS 16384
#define ROWF  131        // 3 coords + 128 features
#define M_OUT 4096       // N / POOL
#define KNN   16
#define FPS_T 512        // fps threads (8 waves)
#define CHUNK 32         // points per fps thread
#define SORT_T 1024

typedef unsigned long long u64;

// spread 4 bits -> every 3rd bit (Morton interleave LUT)
__device__ __constant__ unsigned short c_spread4[16] =
  {0,1,8,9,64,65,72,73,512,513,520,521,576,577,584,585};

__device__ __forceinline__ int cell_of(float x, float y, float z) {
  int ix = (int)floorf((x + 4.0f) * 2.0f); ix = ix < 0 ? 0 : (ix > 15 ? 15 : ix);
  int iy = (int)floorf((y + 4.0f) * 2.0f); iy = iy < 0 ? 0 : (iy > 15 ? 15 : iy);
  int iz = (int)floorf((z + 4.0f) * 2.0f); iz = iz < 0 ? 0 : (iz > 15 ? 15 : iz);
  return (int)c_spread4[ix] | ((int)c_spread4[iy] << 1) | ((int)c_spread4[iz] << 2);
}

// ---------------------------------------------------------------------------
// 1) Extract coords into SoA (orig-index order) for winner lookup + knn.
// ---------------------------------------------------------------------------
__global__ void prep_kernel(const float* __restrict__ x,
                            float* __restrict__ cX, float* __restrict__ cY,
                            float* __restrict__ cZ) {
  const int p = blockIdx.x * blockDim.x + threadIdx.x;
  if (p < N_PTS) {
    cX[p] = x[p * ROWF + 0];
    cY[p] = x[p * ROWF + 1];
    cZ[p] = x[p * ROWF + 2];
  }
}

// ---------------------------------------------------------------------------
// 2) Counting-sort by Morton cell (4096 cells), one 1024-thread block.
//    Produces spatially-sorted gX/gY/gZ/gIdx. Scatter order within a cell is
//    racy but output-invariant (all downstream math keyed by original index).
// ---------------------------------------------------------------------------
__global__ __launch_bounds__(1024, 1)
void sort_kernel(const float* __restrict__ cX, const float* __restrict__ cY,
                 const float* __restrict__ cZ,
                 float* __restrict__ gX, float* __restrict__ gY,
                 float* __restrict__ gZ, int* __restrict__ gIdx) {
  __shared__ unsigned int sh[4096];
  __shared__ unsigned int sws[16];
  const int tid = threadIdx.x, lane = tid & 63, wid = tid >> 6;

#pragma unroll
  for (int i = 0; i < 4; ++i) sh[tid * 4 + i] = 0;
  __syncthreads();

  int cel[16];
#pragma unroll
  for (int j = 0; j < 16; ++j) {
    const int p = tid + SORT_T * j;
    const int c = cell_of(cX[p], cY[p], cZ[p]);
    cel[j] = c;
    atomicAdd(&sh[c], 1u);
  }
  __syncthreads();

  // prefix sum over 4096 counts (4 per thread)
  const unsigned h0 = sh[tid * 4 + 0], h1 = sh[tid * 4 + 1];
  const unsigned h2 = sh[tid * 4 + 2], h3 = sh[tid * 4 + 3];
  const unsigned tsum = h0 + h1 + h2 + h3;
  unsigned inc = tsum;
#pragma unroll
  for (int off = 1; off < 64; off <<= 1) {
    const unsigned v = __shfl_up(inc, off);
    if (lane >= off) inc += v;
  }
  if (lane == 63) sws[wid] = inc;
  __syncthreads();
  if (tid == 0) {
    unsigned run = 0;
#pragma unroll
    for (int w = 0; w < 16; ++w) { const unsigned t = sws[w]; sws[w] = run; run += t; }
  }
  __syncthreads();
  const unsigned base = sws[wid] + inc - tsum;
  sh[tid * 4 + 0] = base;
  sh[tid * 4 + 1] = base + h0;
  sh[tid * 4 + 2] = base + h0 + h1;
  sh[tid * 4 + 3] = base + h0 + h1 + h2;
  __syncthreads();

#pragma unroll
  for (int j = 0; j < 16; ++j) {
    const int p = tid + SORT_T * j;
    const unsigned pos = atomicAdd(&sh[cel[j]], 1u);
    gX[pos] = cX[p]; gY[pos] = cY[p]; gZ[pos] = cZ[p]; gIdx[pos] = p;
  }
}

// ---------------------------------------------------------------------------
// 3) FPS with exact triangle-inequality chunk pruning.
//    512 threads, 32 sorted pts/chunk. min_d2 in LDS (transposed, conflict-
//    free). Persistent regs/thread ~12. Skips are PROVABLY no-op updates ->
//    md trajectory bitwise identical to the unpruned reference.
//    Key = (md_bits<<32) | (N-1-orig_idx): max -> max md, tie -> lowest idx.
// ---------------------------------------------------------------------------
__global__ __launch_bounds__(FPS_T, 1)
void fps_kernel(const float* __restrict__ cX, const float* __restrict__ cY,
                const float* __restrict__ cZ,
                const float* __restrict__ gX, const float* __restrict__ gY,
                const float* __restrict__ gZ, const int* __restrict__ gIdx,
                float* __restrict__ out, float* __restrict__ qc) {
  __shared__ float smd[N_PTS];          // slot (j*FPS_T + tid): lanes stride-1
  __shared__ u64 s_wkey[8];

  const int tid = threadIdx.x, lane = tid & 63;
  const int base = tid * CHUNK;

  // chunk bounding sphere (any center works; r must upper-bound member dist)
  float sx = 0.f, sy = 0.f, sz = 0.f;
#pragma unroll 4
  for (int j = 0; j < CHUNK; ++j) {
    sx += gX[base + j]; sy += gY[base + j]; sz += gZ[base + j];
    smd[j * FPS_T + tid] = __int_as_float(0x7f800000);  // +inf
  }
  const float mx = sx * (1.0f / CHUNK), my = sy * (1.0f / CHUNK), mz = sz * (1.0f / CHUNK);
  float r2 = 0.f;
#pragma unroll 4
  for (int j = 0; j < CHUNK; ++j) {
    const float dx = gX[base + j] - mx, dy = gY[base + j] - my, dz = gZ[base + j] - mz;
    r2 = fmaxf(r2, dx * dx + dy * dy + dz * dz);
  }
  const float r = sqrtf(r2) * 1.000001f + 1e-6f;

  float cmax = __int_as_float(0x7f800000);
  u64 ckey = 0;

  float qx = cX[0], qy = cY[0], qz = cZ[0];
  if (tid == 0) {
    out[0] = qx; out[1] = qy; out[2] = qz;
    qc[0] = qx; qc[1] = qy; qc[2] = qz;
  }
  __syncthreads();

  for (int s = 1; s < M_OUT; ++s) {
    // conservative prune test (margins make skip => provably no member changes)
    const float ddx = mx - qx, ddy = my - qy, ddz = mz - qz;
    const float dd = ddx * ddx + ddy * ddy + ddz * ddz;
    const float lb = sqrtf(dd) * 0.999999f - r;
    const bool skip = (lb > 0.f) && (lb * lb >= cmax * 1.0001f + 1e-12f);

    if (!skip) {
      u64 nk = 0;
#pragma unroll
      for (int g = 0; g < CHUNK / 4; ++g) {
        const float4 vx = *(const float4*)(gX + base + g * 4);
        const float4 vy = *(const float4*)(gY + base + g * 4);
        const float4 vz = *(const float4*)(gZ + base + g * 4);
        const int4  vi = *(const int4*)(gIdx + base + g * 4);
#define FPS_UPD(E, Eoff)                                                        \
        {                                                                       \
          const int slot = (g * 4 + Eoff) * FPS_T + tid;                        \
          const float old = smd[slot];                                          \
          const float dx = vx.E - qx, dy = vy.E - qy, dz = vz.E - qz;           \
          const float d2 = __fadd_rn(__fadd_rn(__fmul_rn(dx, dx),               \
                                               __fmul_rn(dy, dy)),              \
                                     __fmul_rn(dz, dz));                        \
          const float nm = fminf(old, d2);                                      \
          smd[slot] = nm;                                                       \
          const u64 kj = ((u64)__float_as_uint(nm) << 32) |                     \
                         (unsigned)(N_PTS - 1 - vi.E);                          \
          if (kj > nk) nk = kj;                                                 \
        }
        FPS_UPD(x, 0) FPS_UPD(y, 1) FPS_UPD(z, 2) FPS_UPD(w, 3)
#undef FPS_UPD
      }
      ckey = nk;
      cmax = __uint_as_float((unsigned)(nk >> 32));
    }

    // wave max of chunk keys
    u64 k = ckey;
#pragma unroll
    for (int off = 32; off; off >>= 1) {
      const u64 o = __shfl_xor(k, off);
      if (o > k) k = o;
    }
    if (lane == 0) s_wkey[tid >> 6] = k;
    __syncthreads();
    // every wave redundantly reduces the 8 wave keys -> no extra barrier
    u64 kk = s_wkey[lane & 7];
#pragma unroll
    for (int off = 4; off; off >>= 1) {
      const u64 o = __shfl_xor(kk, off);
      if (o > kk) kk = o;
    }
    const int oidx = (N_PTS - 1) - (int)(unsigned)kk;
    qx = cX[oidx]; qy = cY[oidx]; qz = cZ[oidx];
    if (tid == 0) {
      float* orow = out + (size_t)s * ROWF;
      orow[0] = qx; orow[1] = qy; orow[2] = qz;
      float* qrow = qc + s * 3;
      qrow[0] = qx; qrow[1] = qy; qrow[2] = qz;
    }
    __syncthreads();   // protect s_wkey before next step's writes
  }
}

// ---------------------------------------------------------------------------
// 4) KNN top-16 (ties -> lowest index) fused with feature max-pool.
//    One wave per query. Packed u64 (d2_bits<<32 | idx) == lex (d2, idx).
// ---------------------------------------------------------------------------
__global__ __launch_bounds__(256)
void knn_pool_kernel(const float* __restrict__ x,
                     const float* __restrict__ cX, const float* __restrict__ cY,
                     const float* __restrict__ cZ,
                     const float* __restrict__ qc, float* __restrict__ out) {
  const int lane = threadIdx.x & 63;
  const int q = blockIdx.x * 4 + (threadIdx.x >> 6);

  const float qx = qc[q * 3 + 0], qy = qc[q * 3 + 1], qz = qc[q * 3 + 2];

  u64 h[KNN];
#pragma unroll
  for (int k = 0; k < KNN; ++k) h[k] = ~0ULL;

  for (int c = lane; c < N_PTS; c += 64) {
    const float dx = cX[c] - qx, dy = cY[c] - qy, dz = cZ[c] - qz;
    const float d2 = __fadd_rn(__fadd_rn(__fmul_rn(dx, dx), __fmul_rn(dy, dy)),
                               __fmul_rn(dz, dz));
    const u64 e = ((u64)__float_as_uint(d2) << 32) | (unsigned)c;
    if (e < h[KNN - 1]) {
#pragma unroll
      for (int k = KNN - 1; k >= 1; --k) {
        const u64 prev = h[k - 1];
        h[k] = (e < prev) ? prev : ((e < h[k]) ? e : h[k]);
      }
      h[0] = (e < h[0]) ? e : h[0];
    }
  }

  int nbr[KNN];
#pragma unroll
  for (int rr = 0; rr < KNN; ++rr) {
    u64 best = h[0];
#pragma unroll
    for (int off = 32; off; off >>= 1) {
      const u64 o = __shfl_xor(best, off);
      best = (o < best) ? o : best;
    }
    nbr[rr] = (int)(unsigned)(best & 0xffffffffULL);
    if (h[0] == best) {
#pragma unroll
      for (int k = 0; k < KNN - 1; ++k) h[k] = h[k + 1];
      h[KNN - 1] = ~0ULL;
    }
  }

  float a0 = __int_as_float(0xff800000), a1 = a0;
#pragma unroll
  for (int rr = 0; rr < KNN; ++rr) {
    const float* row = x + (size_t)nbr[rr] * ROWF + 3;
    a0 = fmaxf(a0, row[lane]);
    a1 = fmaxf(a1, row[lane + 64]);
  }
  float* orow = out + (size_t)q * ROWF + 3;
  orow[lane] = a0;
  orow[lane + 64] = a1;
}

extern "C" void kernel_launch(void* const* d_in, const int* in_sizes, int n_in,
                              void* d_out, int out_size, void* d_ws, size_t ws_size,
                              hipStream_t stream) {
  const float* x = (const float*)d_in[0];
  float* out = (float*)d_out;

  float* cX   = (float*)d_ws;          // N
  float* cY   = cX + N_PTS;            // N
  float* cZ   = cY + N_PTS;            // N
  float* gX   = cZ + N_PTS;            // N (sorted)
  float* gY   = gX + N_PTS;            // N
  float* gZ   = gY + N_PTS;            // N
  int*   gIdx = (int*)(gZ + N_PTS);    // N
  float* qc   = (float*)(gIdx + N_PTS);// M*3

  hipLaunchKernelGGL(prep_kernel, dim3(16), dim3(1024), 0, stream, x, cX, cY, cZ);
  hipLaunchKernelGGL(sort_kernel, dim3(1), dim3(1024), 0, stream,
                     cX, cY, cZ, gX, gY, gZ, gIdx);
  hipLaunchKernelGGL(fps_kernel, dim3(1), dim3(FPS_T), 0, stream,
                     cX, cY, cZ, gX, gY, gZ, gIdx, out, qc);
  hipLaunchKernelGGL(knn_pool_kernel, dim3(M_OUT / 4), dim3(256), 0, stream,
                     x, cX, cY, cZ, qc, out);
}

// Round 4
// 7428.111 us; speedup vs baseline: 1.6032x; 1.6032x over previous
//
#include <hip/hip_runtime.h>

#define N_PTS 16384
#define ROWF  131        // 3 coords + 128 features
#define M_OUT 4096       // N / POOL
#define KNN   16
#define FPS_T 1024       // fps threads (16 waves)
#define CHUNK 16         // points per fps thread (all state in registers)
#define SORT_T 1024

typedef unsigned long long u64;

// spread 4 bits -> every 3rd bit (Morton interleave LUT)
__device__ __constant__ unsigned short c_spread4[16] =
  {0,1,8,9,64,65,72,73,512,513,520,521,576,577,584,585};

__device__ __forceinline__ int cell_of(float x, float y, float z) {
  int ix = (int)floorf((x + 4.0f) * 2.0f); ix = ix < 0 ? 0 : (ix > 15 ? 15 : ix);
  int iy = (int)floorf((y + 4.0f) * 2.0f); iy = iy < 0 ? 0 : (iy > 15 ? 15 : iy);
  int iz = (int)floorf((z + 4.0f) * 2.0f); iz = iz < 0 ? 0 : (iz > 15 ? 15 : iz);
  return (int)c_spread4[ix] | ((int)c_spread4[iy] << 1) | ((int)c_spread4[iz] << 2);
}

// ---------------------------------------------------------------------------
// 1) Extract coords into SoA (orig-index order) for winner lookup + knn.
// ---------------------------------------------------------------------------
__global__ void prep_kernel(const float* __restrict__ x,
                            float* __restrict__ cX, float* __restrict__ cY,
                            float* __restrict__ cZ) {
  const int p = blockIdx.x * blockDim.x + threadIdx.x;
  if (p < N_PTS) {
    cX[p] = x[p * ROWF + 0];
    cY[p] = x[p * ROWF + 1];
    cZ[p] = x[p * ROWF + 2];
  }
}

// ---------------------------------------------------------------------------
// 2) Counting-sort by Morton cell (4096 cells), one 1024-thread block.
//    Output: slot-major packed float4 (x,y,z,bitcast(origIdx)):
//    sorted rank rk -> chunk c = rk>>4, elem j = rk&15, slot = (j<<10)|c.
//    Thread t of fps owns chunk t; its 16 loads gP4[(j<<10)+t] are coalesced.
//    Within-cell scatter order is racy but output-invariant (all downstream
//    math is keyed by original index; skips are provable no-ops).
// ---------------------------------------------------------------------------
__global__ __launch_bounds__(1024, 1)
void sort_kernel(const float* __restrict__ cX, const float* __restrict__ cY,
                 const float* __restrict__ cZ, float4* __restrict__ gP4) {
  __shared__ unsigned int sh[4096];
  __shared__ unsigned int sws[16];
  const int tid = threadIdx.x, lane = tid & 63, wid = tid >> 6;

#pragma unroll
  for (int i = 0; i < 4; ++i) sh[tid * 4 + i] = 0;
  __syncthreads();

  int cel[16];
#pragma unroll
  for (int j = 0; j < 16; ++j) {
    const int p = tid + SORT_T * j;
    const int c = cell_of(cX[p], cY[p], cZ[p]);
    cel[j] = c;
    atomicAdd(&sh[c], 1u);
  }
  __syncthreads();

  // prefix sum over 4096 counts (4 per thread)
  const unsigned h0 = sh[tid * 4 + 0], h1 = sh[tid * 4 + 1];
  const unsigned h2 = sh[tid * 4 + 2], h3 = sh[tid * 4 + 3];
  const unsigned tsum = h0 + h1 + h2 + h3;
  unsigned inc = tsum;
#pragma unroll
  for (int off = 1; off < 64; off <<= 1) {
    const unsigned v = __shfl_up(inc, off);
    if (lane >= off) inc += v;
  }
  if (lane == 63) sws[wid] = inc;
  __syncthreads();
  if (tid == 0) {
    unsigned run = 0;
#pragma unroll
    for (int w = 0; w < 16; ++w) { const unsigned t = sws[w]; sws[w] = run; run += t; }
  }
  __syncthreads();
  const unsigned base = sws[wid] + inc - tsum;
  sh[tid * 4 + 0] = base;
  sh[tid * 4 + 1] = base + h0;
  sh[tid * 4 + 2] = base + h0 + h1;
  sh[tid * 4 + 3] = base + h0 + h1 + h2;
  __syncthreads();

#pragma unroll
  for (int j = 0; j < 16; ++j) {
    const int p = tid + SORT_T * j;
    const unsigned rk = atomicAdd(&sh[cel[j]], 1u);
    const int slot = ((rk & 15) << 10) | (int)(rk >> 4);
    gP4[slot] = make_float4(cX[p], cY[p], cZ[p], __int_as_float(p));
  }
}

// ---------------------------------------------------------------------------
// 3) FPS, fully register-resident: 1024 threads x 16 points. Coords, orig
//    indices, and min_d2 in VGPRs (static indices only). Inner loop has ZERO
//    memory ops. Triangle-inequality chunk prune with conservative margins:
//    a skip provably changes no member's fminf(md,d2) -> trajectory bitwise
//    identical to the unpruned reference.
//    Key = (md_bits<<32) | (N-1-origIdx): max -> max md, tie -> lowest idx.
//    One barrier/step: s_wkey double-buffered by step parity (md is private).
// ---------------------------------------------------------------------------
__global__ __launch_bounds__(FPS_T, 4)   // 4 waves/EU -> VGPR cap 128
void fps_kernel(const float* __restrict__ cX, const float* __restrict__ cY,
                const float* __restrict__ cZ, const float4* __restrict__ gP4,
                float* __restrict__ out, float* __restrict__ qc) {
  __shared__ u64 s_wkey[2][16];
  const int tid = threadIdx.x, lane = tid & 63, wid = tid >> 6;

  float px[CHUNK], py[CHUNK], pz[CHUNK], md[CHUNK];
  unsigned ni[CHUNK];

#pragma unroll
  for (int j = 0; j < CHUNK; ++j) {
    const float4 v = gP4[(j << 10) + tid];      // coalesced
    px[j] = v.x; py[j] = v.y; pz[j] = v.z;
    ni[j] = (unsigned)(N_PTS - 1 - __float_as_int(v.w));
    md[j] = __int_as_float(0x7f800000);          // +inf
  }

  // chunk bounding sphere (any center; r upper-bounds member distance)
  float sx = 0.f, sy = 0.f, sz = 0.f;
#pragma unroll
  for (int j = 0; j < CHUNK; ++j) { sx += px[j]; sy += py[j]; sz += pz[j]; }
  const float mx = sx * (1.0f / CHUNK), my = sy * (1.0f / CHUNK),
              mz = sz * (1.0f / CHUNK);
  float r2 = 0.f;
#pragma unroll
  for (int j = 0; j < CHUNK; ++j) {
    const float dx = px[j] - mx, dy = py[j] - my, dz = pz[j] - mz;
    r2 = fmaxf(r2, dx * dx + dy * dy + dz * dz);
  }
  const float r = sqrtf(r2) * 1.000001f + 1e-6f;

  float cmax = __int_as_float(0x7f800000);
  u64 ckey = 0;

  float qx = cX[0], qy = cY[0], qz = cZ[0];
  if (tid == 0) {
    out[0] = qx; out[1] = qy; out[2] = qz;
    qc[0] = qx; qc[1] = qy; qc[2] = qz;
  }

  for (int s = 1; s < M_OUT; ++s) {
    // conservative prune (skip => provably no member md changes)
    const float ddx = mx - qx, ddy = my - qy, ddz = mz - qz;
    const float dd = ddx * ddx + ddy * ddy + ddz * ddz;
    const float lb = sqrtf(dd) * 0.999999f - r;
    const bool skip = (lb > 0.f) && (lb * lb >= cmax * 1.0001f + 1e-12f);

    if (!skip) {
      u64 nk = 0;
#pragma unroll
      for (int j = 0; j < CHUNK; ++j) {          // pure VALU, no memory
        const float dx = px[j] - qx, dy = py[j] - qy, dz = pz[j] - qz;
        const float d2 = __fadd_rn(__fadd_rn(__fmul_rn(dx, dx),
                                             __fmul_rn(dy, dy)),
                                   __fmul_rn(dz, dz));
        const float nm = fminf(md[j], d2);
        md[j] = nm;
        const u64 kj = ((u64)__float_as_uint(nm) << 32) | ni[j];
        nk = (kj > nk) ? kj : nk;
      }
      ckey = nk;
      cmax = __uint_as_float((unsigned)(nk >> 32));
    }

    // wave max of chunk keys
    u64 k = ckey;
#pragma unroll
    for (int off = 32; off; off >>= 1) {
      const u64 o = __shfl_xor(k, off);
      if (o > k) k = o;
    }
    const int par = s & 1;
    if (lane == 0) s_wkey[par][wid] = k;
    __syncthreads();                             // the ONLY barrier per step
    u64 kk = s_wkey[par][lane & 15];
#pragma unroll
    for (int off = 8; off; off >>= 1) {
      const u64 o = __shfl_xor(kk, off);
      if (o > kk) kk = o;
    }
    const int oidx = (N_PTS - 1) - (int)(unsigned)kk;
    qx = cX[oidx]; qy = cY[oidx]; qz = cZ[oidx]; // uniform addr, 1 txn/wave
    if (tid == 0) {
      float* orow = out + (size_t)s * ROWF;
      orow[0] = qx; orow[1] = qy; orow[2] = qz;
      qc[s * 3 + 0] = qx; qc[s * 3 + 1] = qy; qc[s * 3 + 2] = qz;
    }
  }
}

// ---------------------------------------------------------------------------
// 4) KNN top-16 (ties -> lowest index) fused with feature max-pool.
//    One wave per query. Packed u64 (d2_bits<<32 | idx) == lex (d2, idx).
// ---------------------------------------------------------------------------
__global__ __launch_bounds__(256)
void knn_pool_kernel(const float* __restrict__ x,
                     const float* __restrict__ cX, const float* __restrict__ cY,
                     const float* __restrict__ cZ,
                     const float* __restrict__ qc, float* __restrict__ out) {
  const int lane = threadIdx.x & 63;
  const int q = blockIdx.x * 4 + (threadIdx.x >> 6);

  const float qx = qc[q * 3 + 0], qy = qc[q * 3 + 1], qz = qc[q * 3 + 2];

  u64 h[KNN];
#pragma unroll
  for (int k = 0; k < KNN; ++k) h[k] = ~0ULL;

  for (int c = lane; c < N_PTS; c += 64) {
    const float dx = cX[c] - qx, dy = cY[c] - qy, dz = cZ[c] - qz;
    const float d2 = __fadd_rn(__fadd_rn(__fmul_rn(dx, dx), __fmul_rn(dy, dy)),
                               __fmul_rn(dz, dz));
    const u64 e = ((u64)__float_as_uint(d2) << 32) | (unsigned)c;
    if (e < h[KNN - 1]) {
#pragma unroll
      for (int k = KNN - 1; k >= 1; --k) {
        const u64 prev = h[k - 1];
        h[k] = (e < prev) ? prev : ((e < h[k]) ? e : h[k]);
      }
      h[0] = (e < h[0]) ? e : h[0];
    }
  }

  int nbr[KNN];
#pragma unroll
  for (int rr = 0; rr < KNN; ++rr) {
    u64 best = h[0];
#pragma unroll
    for (int off = 32; off; off >>= 1) {
      const u64 o = __shfl_xor(best, off);
      best = (o < best) ? o : best;
    }
    nbr[rr] = (int)(unsigned)(best & 0xffffffffULL);
    if (h[0] == best) {
#pragma unroll
      for (int k = 0; k < KNN - 1; ++k) h[k] = h[k + 1];
      h[KNN - 1] = ~0ULL;
    }
  }

  float a0 = __int_as_float(0xff800000), a1 = a0;
#pragma unroll
  for (int rr = 0; rr < KNN; ++rr) {
    const float* row = x + (size_t)nbr[rr] * ROWF + 3;
    a0 = fmaxf(a0, row[lane]);
    a1 = fmaxf(a1, row[lane + 64]);
  }
  float* orow = out + (size_t)q * ROWF + 3;
  orow[lane] = a0;
  orow[lane + 64] = a1;
}

extern "C" void kernel_launch(void* const* d_in, const int* in_sizes, int n_in,
                              void* d_out, int out_size, void* d_ws, size_t ws_size,
                              hipStream_t stream) {
  const float* x = (const float*)d_in[0];
  float* out = (float*)d_out;

  float*  cX  = (float*)d_ws;            // N
  float*  cY  = cX + N_PTS;              // N
  float*  cZ  = cY + N_PTS;              // N
  float4* gP4 = (float4*)(cZ + N_PTS);   // N float4 (16B-aligned: 192KB offset)
  float*  qc  = (float*)(gP4 + N_PTS);   // M*3

  hipLaunchKernelGGL(prep_kernel, dim3(16), dim3(1024), 0, stream, x, cX, cY, cZ);
  hipLaunchKernelGGL(sort_kernel, dim3(1), dim3(1024), 0, stream, cX, cY, cZ, gP4);
  hipLaunchKernelGGL(fps_kernel, dim3(1), dim3(FPS_T), 0, stream,
                     cX, cY, cZ, gP4, out, qc);
  hipLaunchKernelGGL(knn_pool_kernel, dim3(M_OUT / 4), dim3(256), 0, stream,
                     x, cX, cY, cZ, qc, out);
}

// Round 5
// 7275.490 us; speedup vs baseline: 1.6368x; 1.0210x over previous
//
#include <hip/hip_runtime.h>

#define N_PTS 16384
#define ROWF  131        // 3 coords + 128 features
#define M_OUT 4096       // N / POOL
#define KNN   16
#define FPS_T 1024       // fps threads (16 waves)
#define CHUNK 16         // points per fps thread (all state in registers)
#define SORT_T 1024

typedef unsigned long long u64;

// spread 4 bits -> every 3rd bit (Morton interleave LUT)
__device__ __constant__ unsigned short c_spread4[16] =
  {0,1,8,9,64,65,72,73,512,513,520,521,576,577,584,585};

__device__ __forceinline__ int cell_of(float x, float y, float z) {
  int ix = (int)floorf((x + 4.0f) * 2.0f); ix = ix < 0 ? 0 : (ix > 15 ? 15 : ix);
  int iy = (int)floorf((y + 4.0f) * 2.0f); iy = iy < 0 ? 0 : (iy > 15 ? 15 : iy);
  int iz = (int)floorf((z + 4.0f) * 2.0f); iz = iz < 0 ? 0 : (iz > 15 ? 15 : iz);
  return (int)c_spread4[ix] | ((int)c_spread4[iy] << 1) | ((int)c_spread4[iz] << 2);
}

// ---------------------------------------------------------------------------
// 1) Extract coords into packed float4 (x,y,z,unused), orig-index order.
// ---------------------------------------------------------------------------
__global__ void prep_kernel(const float* __restrict__ x,
                            float4* __restrict__ coords4) {
  const int p = blockIdx.x * blockDim.x + threadIdx.x;
  if (p < N_PTS) {
    coords4[p] = make_float4(x[p * ROWF + 0], x[p * ROWF + 1],
                             x[p * ROWF + 2], 0.0f);
  }
}

// ---------------------------------------------------------------------------
// 2) Counting-sort by Morton cell (4096 cells), one 1024-thread block.
//    Output: slot-major packed float4 (x,y,z,bitcast(origIdx)):
//    sorted rank rk -> slot ((rk&15)<<10)|(rk>>4); fps thread t owns sorted
//    ranks [16t,16t+16) and loads gP4[(j<<10)+t] coalesced.
//    Within-cell scatter order is racy but output-invariant.
// ---------------------------------------------------------------------------
__global__ __launch_bounds__(1024, 1)
void sort_kernel(const float4* __restrict__ coords4, float4* __restrict__ gP4) {
  __shared__ unsigned int sh[4096];
  __shared__ unsigned int sws[16];
  const int tid = threadIdx.x, lane = tid & 63, wid = tid >> 6;

#pragma unroll
  for (int i = 0; i < 4; ++i) sh[tid * 4 + i] = 0;
  __syncthreads();

  int cel[16];
#pragma unroll
  for (int j = 0; j < 16; ++j) {
    const float4 v = coords4[tid + SORT_T * j];
    const int c = cell_of(v.x, v.y, v.z);
    cel[j] = c;
    atomicAdd(&sh[c], 1u);
  }
  __syncthreads();

  // prefix sum over 4096 counts (4 per thread)
  const unsigned h0 = sh[tid * 4 + 0], h1 = sh[tid * 4 + 1];
  const unsigned h2 = sh[tid * 4 + 2], h3 = sh[tid * 4 + 3];
  const unsigned tsum = h0 + h1 + h2 + h3;
  unsigned inc = tsum;
#pragma unroll
  for (int off = 1; off < 64; off <<= 1) {
    const unsigned v = __shfl_up(inc, off);
    if (lane >= off) inc += v;
  }
  if (lane == 63) sws[wid] = inc;
  __syncthreads();
  if (tid == 0) {
    unsigned run = 0;
#pragma unroll
    for (int w = 0; w < 16; ++w) { const unsigned t = sws[w]; sws[w] = run; run += t; }
  }
  __syncthreads();
  const unsigned base = sws[wid] + inc - tsum;
  sh[tid * 4 + 0] = base;
  sh[tid * 4 + 1] = base + h0;
  sh[tid * 4 + 2] = base + h0 + h1;
  sh[tid * 4 + 3] = base + h0 + h1 + h2;
  __syncthreads();

#pragma unroll
  for (int j = 0; j < 16; ++j) {
    const int p = tid + SORT_T * j;
    const float4 v = coords4[p];
    const unsigned rk = atomicAdd(&sh[cel[j]], 1u);
    const int slot = (int)(((rk & 15u) << 10) | (rk >> 4));
    gP4[slot] = make_float4(v.x, v.y, v.z, __int_as_float(p));
  }
}

// ---------------------------------------------------------------------------
// 3) FPS, fully register-resident: 1024 threads x 16 points, VGPR cap 128
//    (single-arg launch_bounds -- the (1024,4) hint capped us at 64 and
//    spilled md[] to scratch: 228MB FETCH). Inner loop: zero memory ops.
//    Prune: cached squared threshold u2, recomputed only on dirty steps;
//    conservative margins => a skip provably changes no member's
//    fminf(md,d2) => trajectory bitwise identical to unpruned reference.
//    Key = (md_bits<<32) | (N-1-origIdx): max -> max md, tie -> lowest idx.
//    One barrier/step: s_wkey double-buffered by step parity (md private).
// ---------------------------------------------------------------------------
__global__ __launch_bounds__(FPS_T)
void fps_kernel(const float4* __restrict__ coords4,
                const float4* __restrict__ gP4, float* __restrict__ out) {
  __shared__ u64 s_wkey[2][16];
  const int tid = threadIdx.x, lane = tid & 63, wid = tid >> 6;

  float px[CHUNK], py[CHUNK], pz[CHUNK], md[CHUNK];
  unsigned ni[CHUNK];

#pragma unroll
  for (int j = 0; j < CHUNK; ++j) {
    const float4 v = gP4[(j << 10) + tid];      // coalesced
    px[j] = v.x; py[j] = v.y; pz[j] = v.z;
    ni[j] = (unsigned)(N_PTS - 1 - __float_as_int(v.w));
    md[j] = __int_as_float(0x7f800000);          // +inf
  }

  // chunk bounding sphere (any center; r upper-bounds member distance)
  float sx = 0.f, sy = 0.f, sz = 0.f;
#pragma unroll
  for (int j = 0; j < CHUNK; ++j) { sx += px[j]; sy += py[j]; sz += pz[j]; }
  const float mx = sx * (1.0f / CHUNK), my = sy * (1.0f / CHUNK),
              mz = sz * (1.0f / CHUNK);
  float r2 = 0.f;
#pragma unroll
  for (int j = 0; j < CHUNK; ++j) {
    const float dx = px[j] - mx, dy = py[j] - my, dz = pz[j] - mz;
    r2 = fmaxf(r2, dx * dx + dy * dy + dz * dz);
  }
  const float r = sqrtf(r2) * 1.000001f + 1e-6f;

  float u2 = __int_as_float(0x7f800000);         // +inf -> first step dirty
  u64 ckey = 0;

  const float4 q0 = coords4[0];
  float qx = q0.x, qy = q0.y, qz = q0.z;
  if (tid == 0) { out[0] = qx; out[1] = qy; out[2] = qz; }

  for (int s = 1; s < M_OUT; ++s) {
    // cheap cached prune (skip => provably no member md changes)
    const float ddx = mx - qx, ddy = my - qy, ddz = mz - qz;
    const float dd = ddx * ddx + ddy * ddy + ddz * ddz;
    const bool skip = (dd * 0.999999f > u2);

    if (!skip) {
      u64 nk = 0;
#pragma unroll
      for (int j = 0; j < CHUNK; ++j) {          // pure VALU, no memory
        const float dx = px[j] - qx, dy = py[j] - qy, dz = pz[j] - qz;
        const float d2 = __fadd_rn(__fadd_rn(__fmul_rn(dx, dx),
                                             __fmul_rn(dy, dy)),
                                   __fmul_rn(dz, dz));
        const float nm = fminf(md[j], d2);
        md[j] = nm;
        const u64 kj = ((u64)__float_as_uint(nm) << 32) | ni[j];
        nk = (kj > nk) ? kj : nk;
      }
      ckey = nk;
      // rebuild squared prune threshold from new chunk max (conservative)
      const float cmax = __uint_as_float((unsigned)(nk >> 32));
      const float u = (sqrtf(cmax * 1.0001f + 1e-12f) + r) * 1.000003f;
      u2 = u * u * 1.000001f;
    }

    // wave max of chunk keys
    u64 k = ckey;
#pragma unroll
    for (int off = 32; off; off >>= 1) {
      const u64 o = __shfl_xor(k, off);
      if (o > k) k = o;
    }
    const int par = s & 1;
    if (lane == 0) s_wkey[par][wid] = k;
    __syncthreads();                             // the ONLY barrier per step
    u64 kk = s_wkey[par][lane & 15];
#pragma unroll
    for (int off = 8; off; off >>= 1) {
      const u64 o = __shfl_xor(kk, off);
      if (o > kk) kk = o;
    }
    const int oidx = (N_PTS - 1) - (int)(unsigned)kk;
    const float4 w = coords4[oidx];              // one uniform 16B load
    qx = w.x; qy = w.y; qz = w.z;
    if (tid == 0) {
      float* orow = out + (size_t)s * ROWF;
      orow[0] = qx; orow[1] = qy; orow[2] = qz;
    }
  }
}

// ---------------------------------------------------------------------------
// 4) KNN top-16 (ties -> lowest index) fused with feature max-pool.
//    One wave per query; query coords read from out rows (written by fps).
//    Packed u64 (d2_bits<<32 | idx) == lex (d2, idx).
// ---------------------------------------------------------------------------
__global__ __launch_bounds__(256)
void knn_pool_kernel(const float* __restrict__ x,
                     const float4* __restrict__ coords4,
                     float* __restrict__ out) {
  const int lane = threadIdx.x & 63;
  const int q = blockIdx.x * 4 + (threadIdx.x >> 6);

  const float qx = out[(size_t)q * ROWF + 0];
  const float qy = out[(size_t)q * ROWF + 1];
  const float qz = out[(size_t)q * ROWF + 2];

  u64 h[KNN];
#pragma unroll
  for (int k = 0; k < KNN; ++k) h[k] = ~0ULL;

  for (int c = lane; c < N_PTS; c += 64) {
    const float4 v = coords4[c];                 // coalesced 16B
    const float dx = v.x - qx, dy = v.y - qy, dz = v.z - qz;
    const float d2 = __fadd_rn(__fadd_rn(__fmul_rn(dx, dx), __fmul_rn(dy, dy)),
                               __fmul_rn(dz, dz));
    const u64 e = ((u64)__float_as_uint(d2) << 32) | (unsigned)c;
    if (e < h[KNN - 1]) {
#pragma unroll
      for (int k = KNN - 1; k >= 1; --k) {
        const u64 prev = h[k - 1];
        h[k] = (e < prev) ? prev : ((e < h[k]) ? e : h[k]);
      }
      h[0] = (e < h[0]) ? e : h[0];
    }
  }

  int nbr[KNN];
#pragma unroll
  for (int rr = 0; rr < KNN; ++rr) {
    u64 best = h[0];
#pragma unroll
    for (int off = 32; off; off >>= 1) {
      const u64 o = __shfl_xor(best, off);
      best = (o < best) ? o : best;
    }
    nbr[rr] = (int)(unsigned)(best & 0xffffffffULL);
    if (h[0] == best) {
#pragma unroll
      for (int k = 0; k < KNN - 1; ++k) h[k] = h[k + 1];
      h[KNN - 1] = ~0ULL;
    }
  }

  float a0 = __int_as_float(0xff800000), a1 = a0;
#pragma unroll
  for (int rr = 0; rr < KNN; ++rr) {
    const float* row = x + (size_t)nbr[rr] * ROWF + 3;
    a0 = fmaxf(a0, row[lane]);
    a1 = fmaxf(a1, row[lane + 64]);
  }
  float* orow = out + (size_t)q * ROWF + 3;
  orow[lane] = a0;
  orow[lane + 64] = a1;
}

extern "C" void kernel_launch(void* const* d_in, const int* in_sizes, int n_in,
                              void* d_out, int out_size, void* d_ws, size_t ws_size,
                              hipStream_t stream) {
  const float* x = (const float*)d_in[0];
  float* out = (float*)d_out;

  float4* coords4 = (float4*)d_ws;          // N float4 (256 KB)
  float4* gP4     = coords4 + N_PTS;        // N float4 (256 KB)

  hipLaunchKernelGGL(prep_kernel, dim3(64), dim3(256), 0, stream, x, coords4);
  hipLaunchKernelGGL(sort_kernel, dim3(1), dim3(1024), 0, stream, coords4, gP4);
  hipLaunchKernelGGL(fps_kernel, dim3(1), dim3(FPS_T), 0, stream,
                     coords4, gP4, out);
  hipLaunchKernelGGL(knn_pool_kernel, dim3(M_OUT / 4), dim3(256), 0, stream,
                     x, coords4, out);
}